// Round 2
// baseline (75.005 us; speedup 1.0000x reference)
//
#include <hip/hip_runtime.h>

// out[b,c,h,w] = max over 9x9 offsets of f1*f2pad  ==  f1>=0 ? f1*winMax(f2) : f1*winMin(f2)
// Two separable passes (max, then min) sharing one horizontal buffer:
//   A: horizontal 9-max (global f2 -> hbuf)        [304 jobs]
//   B: vertical 9-max   (hbuf -> vmax LDS, float2) [136 col-pair jobs]
//   C: horizontal 9-min (global f2 -> hbuf)        [304 jobs]
//   D: vertical 9-min + sign-select mult + store   [136 col-pair jobs]
// LDS 22.8 KB -> 6 blocks/CU x 5 waves = 30 waves/CU.

#define HH 38
#define WW 68
#define PLANE (HH * WW)   // 2584
#define NB (16 * 512)
#define HBR 46            // 4 zero pad | 38 data | 4 zero pad
#define TPB 320

__global__ __launch_bounds__(TPB, 8) void corr_sep_kernel(
    const float* __restrict__ f1, const float* __restrict__ f2,
    float* __restrict__ out)
{
    __shared__ float hbuf[HBR * WW];  // 12512 B, one of {row-max, row-min} at a time
    __shared__ float vmax[HH * WW];   // 10336 B, vertical max result

    const int t = threadIdx.x;
    const int base = blockIdx.x * PLANE;
    const float* __restrict__ f2p = f2 + base;

    // ---- zero the 8 pad rows of hbuf (float4); disjoint from phase A writes ----
    for (int i = t; i < 136; i += TPB) {
        int rr = i / 17, q = i % 17;
        int row = (rr < 4) ? rr : rr + HH;            // rows 0..3 and 42..45
        *reinterpret_cast<float4*>(&hbuf[row * WW + q * 4]) = make_float4(0, 0, 0, 0);
    }

    // ---- phase A: horizontal 9-window MAX, f2 read from global (predicated) ----
    if (t < 304) {
        int r = t >> 3, seg = t & 7, c0 = seg * 9;
        float v[17];
        #pragma unroll
        for (int i = 0; i < 17; ++i) {
            int cc = c0 - 4 + i;
            v[i] = (cc >= 0 && cc < WW) ? f2p[r * WW + cc] : 0.0f;
        }
        float d1[16], d2[14], d4[10];
        #pragma unroll
        for (int i = 0; i < 16; ++i) d1[i] = fmaxf(v[i], v[i + 1]);
        #pragma unroll
        for (int i = 0; i < 14; ++i) d2[i] = fmaxf(d1[i], d1[i + 2]);
        #pragma unroll
        for (int i = 0; i < 10; ++i) d4[i] = fmaxf(d2[i], d2[i + 4]);
        #pragma unroll
        for (int k = 0; k < 9; ++k) {
            int col = c0 + k;
            if (col < WW) hbuf[(r + 4) * WW + col] = fmaxf(d4[k], v[k + 8]);
        }
    }
    __syncthreads();

    // ---- phase B: vertical 9-window MAX on column pairs -> vmax ----
    if (t < 136) {
        int cp = t % 34, vs = t / 34;
        int c2 = cp * 2;
        int h0 = (vs == 3) ? 28 : vs * 10;            // rows h0..h0+9 (vs=3 overlaps, same values)
        float2 u[18];
        #pragma unroll
        for (int i = 0; i < 18; ++i)
            u[i] = *reinterpret_cast<const float2*>(&hbuf[(h0 + i) * WW + c2]);
        float2 d1[17], d2[15], d4[10];
        #pragma unroll
        for (int i = 0; i < 17; ++i) d1[i] = make_float2(fmaxf(u[i].x, u[i+1].x), fmaxf(u[i].y, u[i+1].y));
        #pragma unroll
        for (int i = 0; i < 15; ++i) d2[i] = make_float2(fmaxf(d1[i].x, d1[i+2].x), fmaxf(d1[i].y, d1[i+2].y));
        #pragma unroll
        for (int i = 0; i < 10; ++i) d4[i] = make_float2(fmaxf(d2[i].x, d2[i+4].x), fmaxf(d2[i].y, d2[i+4].y));
        #pragma unroll
        for (int k = 0; k < 10; ++k) {
            int h = h0 + k;
            float2 m = make_float2(fmaxf(d4[k].x, u[k+8].x), fmaxf(d4[k].y, u[k+8].y));
            *reinterpret_cast<float2*>(&vmax[h * WW + c2]) = m;
        }
    }
    __syncthreads();

    // ---- phase C: horizontal 9-window MIN, overwrite hbuf data rows (pads stay 0) ----
    if (t < 304) {
        int r = t >> 3, seg = t & 7, c0 = seg * 9;
        float v[17];
        #pragma unroll
        for (int i = 0; i < 17; ++i) {
            int cc = c0 - 4 + i;
            v[i] = (cc >= 0 && cc < WW) ? f2p[r * WW + cc] : 0.0f;
        }
        float d1[16], d2[14], d4[10];
        #pragma unroll
        for (int i = 0; i < 16; ++i) d1[i] = fminf(v[i], v[i + 1]);
        #pragma unroll
        for (int i = 0; i < 14; ++i) d2[i] = fminf(d1[i], d1[i + 2]);
        #pragma unroll
        for (int i = 0; i < 10; ++i) d4[i] = fminf(d2[i], d2[i + 4]);
        #pragma unroll
        for (int k = 0; k < 9; ++k) {
            int col = c0 + k;
            if (col < WW) hbuf[(r + 4) * WW + col] = fminf(d4[k], v[k + 8]);
        }
    }
    __syncthreads();

    // ---- phase D: vertical 9-window MIN + combine + store (float2) ----
    if (t < 136) {
        int cp = t % 34, vs = t / 34;
        int c2 = cp * 2;
        int h0 = (vs == 3) ? 28 : vs * 10;
        float2 u[18];
        #pragma unroll
        for (int i = 0; i < 18; ++i)
            u[i] = *reinterpret_cast<const float2*>(&hbuf[(h0 + i) * WW + c2]);
        float2 d1[17], d2[15], d4[10];
        #pragma unroll
        for (int i = 0; i < 17; ++i) d1[i] = make_float2(fminf(u[i].x, u[i+1].x), fminf(u[i].y, u[i+1].y));
        #pragma unroll
        for (int i = 0; i < 15; ++i) d2[i] = make_float2(fminf(d1[i].x, d1[i+2].x), fminf(d1[i].y, d1[i+2].y));
        #pragma unroll
        for (int i = 0; i < 10; ++i) d4[i] = make_float2(fminf(d2[i].x, d2[i+4].x), fminf(d2[i].y, d2[i+4].y));
        #pragma unroll
        for (int k = 0; k < 10; ++k) {
            int h = h0 + k;
            float2 mn = make_float2(fminf(d4[k].x, u[k+8].x), fminf(d4[k].y, u[k+8].y));
            float2 mx = *reinterpret_cast<const float2*>(&vmax[h * WW + c2]);
            float2 a  = *reinterpret_cast<const float2*>(&f1[base + h * WW + c2]);
            float2 res;
            res.x = a.x * (a.x >= 0.0f ? mx.x : mn.x);
            res.y = a.y * (a.y >= 0.0f ? mx.y : mn.y);
            *reinterpret_cast<float2*>(&out[base + h * WW + c2]) = res;
        }
    }
}

extern "C" void kernel_launch(void* const* d_in, const int* in_sizes, int n_in,
                              void* d_out, int out_size, void* d_ws, size_t ws_size,
                              hipStream_t stream) {
    const float* f1 = (const float*)d_in[0];
    const float* f2 = (const float*)d_in[1];
    float* out = (float*)d_out;
    corr_sep_kernel<<<dim3(NB), dim3(TPB), 0, stream>>>(f1, f2, out);
}

// Round 3
// 57.815 us; speedup vs baseline: 1.2973x; 1.2973x over previous
//
#include <hip/hip_runtime.h>

// out[b,c,h,w] = max over 9x9 offsets of f1*f2pad  ==  f1>=0 ? f1*winMax(f2) : f1*winMin(f2)
// Single combined sweep: horizontal 9-window max+min (global->LDS float2),
// one barrier, vertical 9-window max+min + select-multiply + store.
// LDS 25.0 KB -> 6 blocks/CU x 5 waves = 30 waves/CU. One __syncthreads.

#define HH 38
#define WW 68
#define PLANE (HH * WW)   // 2584
#define NB (16 * 512)
#define HBR 46            // padded rows: 4 zero | 38 data | 4 zero
#define TPB 320

__global__ __launch_bounds__(TPB) void corr_fused_kernel(
    const float* __restrict__ f1, const float* __restrict__ f2,
    float* __restrict__ out)
{
    __shared__ float2 hm[HBR * WW];   // 25024 B: .x = row 9-max, .y = row 9-min

    const int t = threadIdx.x;
    const int base = blockIdx.x * PLANE;
    const float* __restrict__ f2p = f2 + base;

    // ---- phase 0: zero the 8 pad rows (rows 0..3 and 42..45) as float4 ----
    if (t < 272) {                                   // 8 rows x 34 float4
        int rr = t / 34, q = t % 34;
        int row = (rr < 4) ? rr : rr + HH;
        *reinterpret_cast<float4*>(&hm[row * WW + q * 2]) = make_float4(0, 0, 0, 0);
    }

    // ---- phase 1: horizontal 9-window MAX+MIN, f2 from global (predicated) ----
    if (t < 304) {                                   // 38 rows x 8 segments
        int r = t >> 3, seg = t & 7, c0 = seg * 9;
        float v[17];
        #pragma unroll
        for (int i = 0; i < 17; ++i) {
            int cc = c0 - 4 + i;
            v[i] = (cc >= 0 && cc < WW) ? f2p[r * WW + cc] : 0.0f;
        }
        float ax[16], an[16];
        #pragma unroll
        for (int i = 0; i < 16; ++i) { ax[i] = fmaxf(v[i], v[i+1]); an[i] = fminf(v[i], v[i+1]); }
        float bx[14], bn[14];
        #pragma unroll
        for (int i = 0; i < 14; ++i) { bx[i] = fmaxf(ax[i], ax[i+2]); bn[i] = fminf(an[i], an[i+2]); }
        float cx[10], cn[10];
        #pragma unroll
        for (int i = 0; i < 10; ++i) { cx[i] = fmaxf(bx[i], bx[i+4]); cn[i] = fminf(bn[i], bn[i+4]); }
        #pragma unroll
        for (int k = 0; k < 9; ++k) {                // window = v[k..k+8]
            int col = c0 + k;
            if (col < WW)
                hm[(r + 4) * WW + col] =
                    make_float2(fmaxf(cx[k], v[k+8]), fminf(cn[k], v[k+8]));
        }
    }
    __syncthreads();

    // ---- phase 2: vertical 9-window MAX+MIN + sign-select multiply + store ----
    if (t < 272) {                                   // 68 cols x 4 segments of 10 rows
        int col = t % WW, vs = t / WW;
        int h0 = (vs == 3) ? 28 : vs * 10;           // vs=3 overlaps rows 28-29 (same values)
        float2 u[18];
        #pragma unroll
        for (int i = 0; i < 18; ++i) u[i] = hm[(h0 + i) * WW + col];  // padded rows h0..h0+17
        float ax[17], an[17];
        #pragma unroll
        for (int i = 0; i < 17; ++i) { ax[i] = fmaxf(u[i].x, u[i+1].x); an[i] = fminf(u[i].y, u[i+1].y); }
        float bx[15], bn[15];
        #pragma unroll
        for (int i = 0; i < 15; ++i) { bx[i] = fmaxf(ax[i], ax[i+2]); bn[i] = fminf(an[i], an[i+2]); }
        float cx[10], cn[10];
        #pragma unroll
        for (int i = 0; i < 10; ++i) { cx[i] = fmaxf(bx[i], bx[i+4]); cn[i] = fminf(bn[i], bn[i+4]); }
        #pragma unroll
        for (int k = 0; k < 10; ++k) {               // output row h = h0+k, window u[k..k+8]
            int h = h0 + k;
            float mx = fmaxf(cx[k], u[k+8].x);
            float mn = fminf(cn[k], u[k+8].y);
            int idx = base + h * WW + col;
            float a = f1[idx];
            out[idx] = a * (a >= 0.0f ? mx : mn);
        }
    }
}

extern "C" void kernel_launch(void* const* d_in, const int* in_sizes, int n_in,
                              void* d_out, int out_size, void* d_ws, size_t ws_size,
                              hipStream_t stream) {
    const float* f1 = (const float*)d_in[0];
    const float* f2 = (const float*)d_in[1];
    float* out = (float*)d_out;
    corr_fused_kernel<<<dim3(NB), dim3(TPB), 0, stream>>>(f1, f2, out);
}

// Round 4
// 54.323 us; speedup vs baseline: 1.3807x; 1.0643x over previous
//
#include <hip/hip_runtime.h>

// out = f1>=0 ? f1*winMax9x9(f2pad) : f1*winMin9x9(f2pad), separable sweep.
// 8 planes per block, software-pipelined: next plane's f2 (and this plane's f1)
// global loads are issued before raw s_barriers that wait only lgkmcnt(0), so
// HBM latency hides under the current plane's horizontal+vertical passes.
// (__syncthreads would drain vmcnt(0) and kill the pipeline -- m97 finding.)

#define HH 38
#define WW 68
#define PLANE (HH * WW)        // 2584
#define S2S 84                 // s2 stride: 4 zero | 68 data | 8 zero | 4 slack (84%32=20 -> spread banks)
#define HBR 46                 // hm rows: 4 zero | 38 data | 4 zero
#define TPB 320
#define PPB 8                  // planes per block
#define NB ((16 * 512) / PPB)  // 1024 blocks = 4 resident/CU, single round

#define BAR() do { asm volatile("s_waitcnt lgkmcnt(0)" ::: "memory"); \
                   __builtin_amdgcn_s_barrier();                      \
                   __builtin_amdgcn_sched_barrier(0); } while (0)

__global__ __launch_bounds__(TPB) void corr_pipe_kernel(
    const float* __restrict__ f1, const float* __restrict__ f2,
    float* __restrict__ out)
{
    __shared__ float  s2[HH * S2S];   // 12768 B, padded f2 plane
    __shared__ float2 hm[HBR * WW];   // 25024 B, .x=row 9-max, .y=row 9-min

    const int t = threadIdx.x;
    const long long base0 = (long long)blockIdx.x * (PPB * PLANE);

    // ---- once: zero s2 pad cols and hm pad rows (never rewritten) ----
    for (int i = t; i < 456; i += TPB) {            // 38 rows x 12 pad cols
        int r = i / 12, j = i % 12;
        int c = (j < 4) ? j : j + 68;               // cols 0..3 and 72..79
        s2[r * S2S + c] = 0.0f;
    }
    if (t < 272) {                                  // 8 pad rows x 34 float4
        int rr = t / 34, q = t % 34;
        int row = (rr < 4) ? rr : rr + HH;
        *reinterpret_cast<float4*>(&hm[row * WW + q * 2]) = make_float4(0, 0, 0, 0);
    }

    // invariant staging decomposition: 646 float4 jobs = t, t+320, (t<6: 640+t)
    const int j0 = t, j1 = t + TPB, j2 = 640 + t;
    const int r0 = j0 / 17, q0 = j0 % 17;
    const int r1 = j1 / 17, q1 = j1 % 17;
    const int r2 = j2 / 17, q2 = j2 % 17;
    const bool has2 = (t < 6);

    // invariant vertical-pass decomposition: 272 jobs = 68 cols x 4 row-segments
    const int col = t % WW;
    const int vs  = t / WW;
    const int h0  = (vs == 3) ? 28 : vs * 10;       // overlap trick: no row predicate

    // ---- prefetch plane 0 ----
    float4 pre0, pre1, pre2 = make_float4(0, 0, 0, 0);
    {
        const float* p = f2 + base0;
        pre0 = *reinterpret_cast<const float4*>(p + 4 * j0);
        pre1 = *reinterpret_cast<const float4*>(p + 4 * j1);
        if (has2) pre2 = *reinterpret_cast<const float4*>(p + 4 * j2);
    }

    for (int pp = 0; pp < PPB; ++pp) {
        const long long base = base0 + (long long)pp * PLANE;

        // (A) registers -> s2 (waits vmcnt for the prefetched regs only)
        *reinterpret_cast<float4*>(&s2[r0 * S2S + 4 + 4 * q0]) = pre0;
        *reinterpret_cast<float4*>(&s2[r1 * S2S + 4 + 4 * q1]) = pre1;
        if (has2) *reinterpret_cast<float4*>(&s2[r2 * S2S + 4 + 4 * q2]) = pre2;

        // (B) issue next plane's f2 loads -- stay in flight across raw barriers
        if (pp + 1 < PPB) {
            const float* p = f2 + base + PLANE;
            pre0 = *reinterpret_cast<const float4*>(p + 4 * j0);
            pre1 = *reinterpret_cast<const float4*>(p + 4 * j1);
            if (has2) pre2 = *reinterpret_cast<const float4*>(p + 4 * j2);
        }

        // (F) issue this plane's f1 loads -- consumed in the vertical pass
        float fr[10];
        if (t < 272) {
            #pragma unroll
            for (int k = 0; k < 10; ++k)
                fr[k] = f1[base + (h0 + k) * WW + col];
        }

        BAR();  // s2 ready (lgkm only; global loads keep flying)

        // ---- horizontal 9-window MAX+MIN: s2 -> hm ----
        if (t < 304) {                              // 38 rows x 8 segments
            int r = t >> 3, seg = t & 7, c0 = seg * 9;
            float v[17];
            #pragma unroll
            for (int i = 0; i < 17; ++i) v[i] = s2[r * S2S + c0 + i];
            float ax[16], an[16];
            #pragma unroll
            for (int i = 0; i < 16; ++i) { ax[i] = fmaxf(v[i], v[i+1]); an[i] = fminf(v[i], v[i+1]); }
            float bx[14], bn[14];
            #pragma unroll
            for (int i = 0; i < 14; ++i) { bx[i] = fmaxf(ax[i], ax[i+2]); bn[i] = fminf(an[i], an[i+2]); }
            float cx[10], cn[10];
            #pragma unroll
            for (int i = 0; i < 10; ++i) { cx[i] = fmaxf(bx[i], bx[i+4]); cn[i] = fminf(bn[i], bn[i+4]); }
            #pragma unroll
            for (int k = 0; k < 9; ++k) {           // window = v[k..k+8]
                int c = c0 + k;
                if (c < WW)
                    hm[(r + 4) * WW + c] =
                        make_float2(fmaxf(cx[k], v[k+8]), fminf(cn[k], v[k+8]));
            }
        }

        BAR();  // hm ready; s2 free for next plane's (A)

        // ---- vertical 9-window MAX+MIN + sign-select multiply + store ----
        if (t < 272) {
            float2 u[18];
            #pragma unroll
            for (int i = 0; i < 18; ++i) u[i] = hm[(h0 + i) * WW + col];
            float ax[17], an[17];
            #pragma unroll
            for (int i = 0; i < 17; ++i) { ax[i] = fmaxf(u[i].x, u[i+1].x); an[i] = fminf(u[i].y, u[i+1].y); }
            float bx[15], bn[15];
            #pragma unroll
            for (int i = 0; i < 15; ++i) { bx[i] = fmaxf(ax[i], ax[i+2]); bn[i] = fminf(an[i], an[i+2]); }
            float cx[10], cn[10];
            #pragma unroll
            for (int i = 0; i < 10; ++i) { cx[i] = fmaxf(bx[i], bx[i+4]); cn[i] = fminf(bn[i], bn[i+4]); }
            #pragma unroll
            for (int k = 0; k < 10; ++k) {          // window = u[k..k+8]
                float mx = fmaxf(cx[k], u[k+8].x);
                float mn = fminf(cn[k], u[k+8].y);
                float a  = fr[k];
                out[base + (h0 + k) * WW + col] = a * (a >= 0.0f ? mx : mn);
            }
        }
        // no third barrier: next iteration's BAR() (after A/B/F) separates
        // this plane's hm readers from next plane's hm writers.
    }
}

extern "C" void kernel_launch(void* const* d_in, const int* in_sizes, int n_in,
                              void* d_out, int out_size, void* d_ws, size_t ws_size,
                              hipStream_t stream) {
    const float* f1 = (const float*)d_in[0];
    const float* f2 = (const float*)d_in[1];
    float* out = (float*)d_out;
    corr_pipe_kernel<<<dim3(NB), dim3(TPB), 0, stream>>>(f1, f2, out);
}

// Round 5
// 43.544 us; speedup vs baseline: 1.7225x; 1.2475x over previous
//
#include <hip/hip_runtime.h>

// out = f1>=0 ? f1*winMax9x9(f2pad) : f1*winMin9x9(f2pad)  (separable 9-window)
// Vertical-first: each thread computes a 10-row column segment of the vertical
// 9-window max/min via van Herk prefix/suffix (reads f2 straight from global,
// coalesced lane=column), writes to bank-uniform LDS planes; ONE lgkm-only
// barrier; horizontal van Herk + sign-select multiply + store.
// LDS 24.6 KB -> 6 blocks/CU x 5 waves = 30 waves/CU.

#define HH 38
#define WW 68
#define PLANE (HH * WW)    // 2584
#define HMS 81             // LDS row stride (floats): 4 left pad | 68 data | 9 right pad
#define TPB 320
#define NB (16 * 512)

#define BAR() do { asm volatile("s_waitcnt lgkmcnt(0)" ::: "memory"); \
                   __builtin_amdgcn_s_barrier();                      \
                   __builtin_amdgcn_sched_barrier(0); } while (0)

__global__ __launch_bounds__(TPB) void corr_vh_kernel(
    const float* __restrict__ f1, const float* __restrict__ f2,
    float* __restrict__ out)
{
    __shared__ float hmx[HH * HMS];   // vertical 9-window max, padded cols
    __shared__ float hmn[HH * HMS];   // vertical 9-window min

    const int t = threadIdx.x;
    const int base = blockIdx.x * PLANE;
    const float* __restrict__ f2p = f2 + base;

    // ---- zero pad columns (phys 0..3 and 72..79) of both planes ----
    for (int i = t; i < 456; i += TPB) {          // 38 rows x 12 pad cols
        int r = i / 12, j = i % 12;
        int c = (j < 4) ? j : j + 68;
        hmx[r * HMS + c] = 0.0f;
        hmn[r * HMS + c] = 0.0f;
    }

    // ---- prefetch f1 for the horizontal phase (in flight across the barrier) ----
    const int hr = t >> 3, hseg = t & 7, hc0 = hseg * 9;
    float fr[9];
    if (t < 304) {
        #pragma unroll
        for (int k = 0; k < 9; ++k)
            fr[k] = (hc0 + k < WW) ? f1[base + hr * WW + hc0 + k] : 0.0f;
    }

    // ---- vertical 9-window MAX+MIN via van Herk, global -> LDS ----
    if (t < 272) {                                // 68 cols x 4 segments of 10 rows
        const int col = t % WW, seg = t / WW;
        const int h0 = (seg == 3) ? 28 : seg * 10;   // overlap trick, no row predicate on out
        float v[18];
        #pragma unroll
        for (int i = 0; i < 18; ++i) {
            int row = h0 - 4 + i;
            v[i] = (row >= 0 && row < HH) ? f2p[row * WW + col] : 0.0f;
        }
        float S[9], P[9];
        // max: suffix over v[0..8], prefix over v[9..17]; window k = v[k..k+8]
        S[8] = v[8];
        #pragma unroll
        for (int i = 7; i >= 0; --i) S[i] = fmaxf(v[i], S[i + 1]);
        P[0] = v[9];
        #pragma unroll
        for (int i = 1; i < 9; ++i) P[i] = fmaxf(P[i - 1], v[9 + i]);
        hmx[(h0 + 0) * HMS + 4 + col] = S[0];
        #pragma unroll
        for (int k = 1; k < 9; ++k)
            hmx[(h0 + k) * HMS + 4 + col] = fmaxf(S[k], P[k - 1]);
        hmx[(h0 + 9) * HMS + 4 + col] = P[8];
        // min
        S[8] = v[8];
        #pragma unroll
        for (int i = 7; i >= 0; --i) S[i] = fminf(v[i], S[i + 1]);
        P[0] = v[9];
        #pragma unroll
        for (int i = 1; i < 9; ++i) P[i] = fminf(P[i - 1], v[9 + i]);
        hmn[(h0 + 0) * HMS + 4 + col] = S[0];
        #pragma unroll
        for (int k = 1; k < 9; ++k)
            hmn[(h0 + k) * HMS + 4 + col] = fminf(S[k], P[k - 1]);
        hmn[(h0 + 9) * HMS + 4 + col] = P[8];
    }

    BAR();   // LDS ready; f1 prefetch loads keep flying (no vmcnt drain)

    // ---- horizontal 9-window MAX+MIN via van Herk + combine + store ----
    if (t < 304) {                                // 38 rows x 8 segments of 9 cols
        float u[17];
        float S[9], P[9], wx[9];
        // max from hmx: u[i] = phys col hc0+i = real col hc0-4+i
        #pragma unroll
        for (int i = 0; i < 17; ++i) u[i] = hmx[hr * HMS + hc0 + i];
        S[8] = u[8];
        #pragma unroll
        for (int i = 7; i >= 0; --i) S[i] = fmaxf(u[i], S[i + 1]);
        P[0] = u[9];
        #pragma unroll
        for (int i = 1; i < 9; ++i) P[i] = fmaxf(P[i - 1], u[9 + i]);
        wx[0] = S[0];
        #pragma unroll
        for (int k = 1; k < 9; ++k) wx[k] = fmaxf(S[k], P[k - 1]);
        // min from hmn
        #pragma unroll
        for (int i = 0; i < 17; ++i) u[i] = hmn[hr * HMS + hc0 + i];
        S[8] = u[8];
        #pragma unroll
        for (int i = 7; i >= 0; --i) S[i] = fminf(u[i], S[i + 1]);
        P[0] = u[9];
        #pragma unroll
        for (int i = 1; i < 9; ++i) P[i] = fminf(P[i - 1], u[9 + i]);
        #pragma unroll
        for (int k = 0; k < 9; ++k) {
            int c = hc0 + k;
            if (c < WW) {
                float wn = (k == 0) ? S[0] : fminf(S[k], P[k - 1]);
                float a = fr[k];
                out[base + hr * WW + c] = a * (a >= 0.0f ? wx[k] : wn);
            }
        }
    }
}

extern "C" void kernel_launch(void* const* d_in, const int* in_sizes, int n_in,
                              void* d_out, int out_size, void* d_ws, size_t ws_size,
                              hipStream_t stream) {
    const float* f1 = (const float*)d_in[0];
    const float* f2 = (const float*)d_in[1];
    float* out = (float*)d_out;
    corr_vh_kernel<<<dim3(NB), dim3(TPB), 0, stream>>>(f1, f2, out);
}